// Round 1
// baseline (2045.009 us; speedup 1.0000x reference)
//
#include <hip/hip_runtime.h>
#include <math.h>

#define DM 256      // D_MODEL
#define NL 4        // N_LAYERS
#define DI 512      // D_INNER
#define DS 16       // D_STATE
#define DC 4        // D_CONV
#define DR 16       // DT_RANK
#define NC 10       // NUM_CLASSES
#define NB 8        // B
#define LL 1024     // L
#define MR (NB*LL)  // 8192 rows

__device__ __forceinline__ float silu_f(float x) {
    return x * (1.0f / (1.0f + __expf(-x)));
}

// h[m][d] = x[m] * w[d] + b[d]
__global__ void input_proj_kernel(const float* __restrict__ x, const float* __restrict__ w,
                                  const float* __restrict__ b, float* __restrict__ h) {
    int t = blockIdx.x * 256 + threadIdx.x;
    if (t >= MR * DM) return;
    int d = t & (DM - 1);
    int m = t >> 8;
    h[t] = x[m] * w[d] + b[d];
}

// one block (256 thr) per row of 256
__global__ __launch_bounds__(256) void layernorm_kernel(const float* __restrict__ in,
        const float* __restrict__ w, const float* __restrict__ b, float* __restrict__ out) {
    int row = blockIdx.x, t = threadIdx.x;
    float v = in[row * DM + t];
    float s = v, q = v * v;
#pragma unroll
    for (int o = 32; o >= 1; o >>= 1) { s += __shfl_xor(s, o); q += __shfl_xor(q, o); }
    __shared__ float red[8];
    int wid = t >> 6;
    if ((t & 63) == 0) { red[wid] = s; red[4 + wid] = q; }
    __syncthreads();
    s = red[0] + red[1] + red[2] + red[3];
    q = red[4] + red[5] + red[6] + red[7];
    float mu = s * (1.0f / DM);
    float var = q * (1.0f / DM) - mu * mu;
    float rs = rsqrtf(var + 1e-5f);
    out[row * DM + t] = (v - mu) * rs * w[t] + b[t];
}

// C[M,N] = A[M,K] @ W[N,K]^T (+bias) ; EPI==1: C += ...
// 64x64 tile, BK=16, 256 threads, 4x4 micro-tile. M multiple of 64, K multiple of 16.
template<int EPI>
__global__ __launch_bounds__(256) void gemm_kernel(
        const float* __restrict__ A, int lda,
        const float* __restrict__ W, const float* __restrict__ bias,
        float* __restrict__ C, int ldc, int N, int K) {
    __shared__ float As[16][68];
    __shared__ float Ws[16][68];
    int tid = threadIdx.x;
    int bm = blockIdx.x * 64, bn = blockIdx.y * 64;
    int tx = tid & 15, ty = tid >> 4;
    int lr = tid >> 2;            // load row 0..63
    int lk = (tid & 3) << 2;      // load k offset 0,4,8,12
    float acc[4][4] = {};
    for (int k0 = 0; k0 < K; k0 += 16) {
        float4 av = *reinterpret_cast<const float4*>(&A[(size_t)(bm + lr) * lda + k0 + lk]);
        float4 wv = make_float4(0.f, 0.f, 0.f, 0.f);
        if (bn + lr < N) wv = *reinterpret_cast<const float4*>(&W[(size_t)(bn + lr) * K + k0 + lk]);
        As[lk + 0][lr] = av.x; As[lk + 1][lr] = av.y; As[lk + 2][lr] = av.z; As[lk + 3][lr] = av.w;
        Ws[lk + 0][lr] = wv.x; Ws[lk + 1][lr] = wv.y; Ws[lk + 2][lr] = wv.z; Ws[lk + 3][lr] = wv.w;
        __syncthreads();
#pragma unroll
        for (int kk = 0; kk < 16; kk++) {
            float4 a4 = *reinterpret_cast<const float4*>(&As[kk][ty * 4]);
            float4 b4 = *reinterpret_cast<const float4*>(&Ws[kk][tx * 4]);
            acc[0][0] += a4.x * b4.x; acc[0][1] += a4.x * b4.y; acc[0][2] += a4.x * b4.z; acc[0][3] += a4.x * b4.w;
            acc[1][0] += a4.y * b4.x; acc[1][1] += a4.y * b4.y; acc[1][2] += a4.y * b4.z; acc[1][3] += a4.y * b4.w;
            acc[2][0] += a4.z * b4.x; acc[2][1] += a4.z * b4.y; acc[2][2] += a4.z * b4.z; acc[2][3] += a4.z * b4.w;
            acc[3][0] += a4.w * b4.x; acc[3][1] += a4.w * b4.y; acc[3][2] += a4.w * b4.z; acc[3][3] += a4.w * b4.w;
        }
        __syncthreads();
    }
    int cm = bm + ty * 4, cn = bn + tx * 4;
#pragma unroll
    for (int i = 0; i < 4; i++) {
#pragma unroll
        for (int j = 0; j < 4; j++) {
            int col = cn + j;
            if (col < N) {
                float v = acc[i][j];
                if (bias) v += bias[col];
                if (EPI == 1) v += C[(size_t)(cm + i) * ldc + col];
                C[(size_t)(cm + i) * ldc + col] = v;
            }
        }
    }
}

// u[m][d] = silu( sum_k cw[d][k] * u_pre[m-3+k][d] + cb[d] ), u_pre = xz cols 0..511 (ld 1024)
__global__ void conv_silu_kernel(const float* __restrict__ xz, const float* __restrict__ cw,
                                 const float* __restrict__ cb, float* __restrict__ u) {
    int t = blockIdx.x * 256 + threadIdx.x;
    if (t >= MR * DI) return;
    int d = t & (DI - 1);
    int m = t >> 9;
    int l = m & (LL - 1);
    const float4 w4 = *reinterpret_cast<const float4*>(&cw[d * 4]);
    float acc = cb[d] + w4.w * xz[(size_t)m * 1024 + d];
    if (l >= 1) acc += w4.z * xz[(size_t)(m - 1) * 1024 + d];
    if (l >= 2) acc += w4.y * xz[(size_t)(m - 2) * 1024 + d];
    if (l >= 3) acc += w4.x * xz[(size_t)(m - 3) * 1024 + d];
    u[t] = silu_f(acc);
}

// delta[m][d] = softplus( sum_k x_dbl[m][k] * dtw[d][k] + dtb[d] )
__global__ __launch_bounds__(256) void dtproj_kernel(const float* __restrict__ x_dbl,
        const float* __restrict__ dtw, const float* __restrict__ dtb, float* __restrict__ delta) {
    int m = blockIdx.x, t = threadIdx.x;
    __shared__ float dts[DR];
    if (t < DR) dts[t] = x_dbl[(size_t)m * 48 + t];
    __syncthreads();
#pragma unroll
    for (int p = 0; p < 2; p++) {
        int d = t + p * 256;
        float acc = dtb[d];
#pragma unroll
        for (int k = 0; k < DR; k++) acc += dtw[d * DR + k] * dts[k];
        float sp = (acc > 20.0f) ? acc : log1pf(expf(acc));
        delta[(size_t)m * DI + d] = sp;
    }
}

// one lane per (b,d,n): h_l = exp(delta*A)*h_{l-1} + delta*B*u ; y = sum_n h*C + u*D
__global__ __launch_bounds__(256) void scan_kernel(
        const float* __restrict__ u, const float* __restrict__ delta,
        const float* __restrict__ x_dbl, const float* __restrict__ A_log,
        const float* __restrict__ Dp, float* __restrict__ y) {
    int tid = threadIdx.x;
    int n = tid & 15, dloc = tid >> 4;             // 16 channels x 16 states
    int b = blockIdx.x >> 5;
    int d = ((blockIdx.x & 31) << 4) + dloc;
    float Aval = -expf(A_log[d * DS + n]);
    float Dval = Dp[d];
    float h = 0.f;
    const float* dl = delta + (size_t)(b * LL) * DI + d;
    const float* uu = u + (size_t)(b * LL) * DI + d;
    const float* xb = x_dbl + (size_t)(b * LL) * 48;
    float* yy = y + (size_t)(b * LL) * DI + d;
    float dv = dl[0], uv = uu[0], Bv = xb[16 + n], Cv = xb[32 + n];
    for (int l = 0; l < LL; l++) {
        float dv_n = 0.f, uv_n = 0.f, Bv_n = 0.f, Cv_n = 0.f;
        if (l + 1 < LL) {
            dv_n = dl[(size_t)(l + 1) * DI];
            uv_n = uu[(size_t)(l + 1) * DI];
            Bv_n = xb[(size_t)(l + 1) * 48 + 16 + n];
            Cv_n = xb[(size_t)(l + 1) * 48 + 32 + n];
        }
        float dA = __expf(dv * Aval);
        h = dA * h + (dv * Bv) * uv;
        float p = h * Cv;
        p += __shfl_xor(p, 1);
        p += __shfl_xor(p, 2);
        p += __shfl_xor(p, 4);
        p += __shfl_xor(p, 8);
        if (n == 0) yy[(size_t)l * DI] = p + Dval * uv;
        dv = dv_n; uv = uv_n; Bv = Bv_n; Cv = Cv_n;
    }
}

// y[m][d] *= silu(res[m][d]),  res = xz cols 512..1023
__global__ void gate_kernel(float* __restrict__ y, const float* __restrict__ xz) {
    int t = blockIdx.x * 256 + threadIdx.x;
    if (t >= MR * DI) return;
    int d = t & (DI - 1);
    int m = t >> 9;
    float r = xz[(size_t)m * 1024 + 512 + d];
    y[t] *= silu_f(r);
}

// pooled[b][dm] = mean_l ln[b*L+l][dm]
__global__ void pool_kernel(const float* __restrict__ ln, float* __restrict__ pooled) {
    int t = blockIdx.x * 256 + threadIdx.x;
    if (t >= NB * DM) return;
    int b = t >> 8, dmn = t & 255;
    float s = 0.f;
    for (int l = 0; l < LL; l++) s += ln[(size_t)(b * LL + l) * DM + dmn];
    pooled[t] = s * (1.0f / LL);
}

__global__ void cls_kernel(const float* __restrict__ pooled, const float* __restrict__ cw,
                           const float* __restrict__ cb, float* __restrict__ out) {
    int t = threadIdx.x;
    if (t >= NB * NC) return;
    int b = t / NC, c = t % NC;
    float s = cb[c];
    for (int k = 0; k < DM; k++) s += pooled[b * DM + k] * cw[c * DM + k];
    out[t] = s;
}

extern "C" void kernel_launch(void* const* d_in, const int* in_sizes, int n_in,
                              void* d_out, int out_size, void* d_ws, size_t ws_size,
                              hipStream_t stream) {
    const float* x       = (const float*)d_in[0];
    const float* input_w = (const float*)d_in[1];
    const float* input_b = (const float*)d_in[2];
    const float* ln_w    = (const float*)d_in[3];
    const float* ln_b    = (const float*)d_in[4];
    const float* ipw     = (const float*)d_in[5];
    const float* ipb     = (const float*)d_in[6];
    const float* cw      = (const float*)d_in[7];
    const float* cb      = (const float*)d_in[8];
    const float* xpw     = (const float*)d_in[9];
    const float* dtw     = (const float*)d_in[10];
    const float* dtb     = (const float*)d_in[11];
    const float* A_log   = (const float*)d_in[12];
    const float* Dp      = (const float*)d_in[13];
    const float* opw     = (const float*)d_in[14];
    const float* opb     = (const float*)d_in[15];
    const float* norm_w  = (const float*)d_in[16];
    const float* norm_b  = (const float*)d_in[17];
    const float* cls_w   = (const float*)d_in[18];
    const float* cls_b   = (const float*)d_in[19];
    float* out = (float*)d_out;
    float* ws = (float*)d_ws;

    float* hres   = ws;                           // MR*DM      = 2M floats
    float* xz     = hres + (size_t)MR * DM;       // MR*1024    = 8M
    float* u      = xz + (size_t)MR * 2 * DI;     // MR*DI      = 4M
    float* delta  = u + (size_t)MR * DI;          // MR*DI      = 4M
    float* ybuf   = delta + (size_t)MR * DI;      // MR*DI      = 4M (also LN buffer)
    float* x_dbl  = ybuf + (size_t)MR * DI;       // MR*48
    float* pooled = x_dbl + (size_t)MR * 48;      // NB*DM

    input_proj_kernel<<<MR * DM / 256, 256, 0, stream>>>(x, input_w, input_b, hres);

    for (int i = 0; i < NL; i++) {
        layernorm_kernel<<<MR, 256, 0, stream>>>(hres, ln_w + i * DM, ln_b + i * DM, ybuf);
        gemm_kernel<0><<<dim3(MR / 64, (2 * DI) / 64), 256, 0, stream>>>(
            ybuf, DM, ipw + (size_t)i * 2 * DI * DM, ipb + i * 2 * DI, xz, 2 * DI, 2 * DI, DM);
        conv_silu_kernel<<<MR * DI / 256, 256, 0, stream>>>(xz, cw + i * DI * DC, cb + i * DI, u);
        gemm_kernel<0><<<dim3(MR / 64, 1), 256, 0, stream>>>(
            u, DI, xpw + (size_t)i * 48 * DI, nullptr, x_dbl, 48, 48, DI);
        dtproj_kernel<<<MR, 256, 0, stream>>>(x_dbl, dtw + i * DI * DR, dtb + i * DI, delta);
        scan_kernel<<<256, 256, 0, stream>>>(u, delta, x_dbl, A_log + i * DI * DS, Dp + i * DI, ybuf);
        gate_kernel<<<MR * DI / 256, 256, 0, stream>>>(ybuf, xz);
        gemm_kernel<1><<<dim3(MR / 64, DM / 64), 256, 0, stream>>>(
            ybuf, DI, opw + (size_t)i * DM * DI, opb + i * DM, hres, DM, DM, DI);
    }

    layernorm_kernel<<<MR, 256, 0, stream>>>(hres, norm_w, norm_b, ybuf);
    pool_kernel<<<NB * DM / 256, 256, 0, stream>>>(ybuf, pooled);
    cls_kernel<<<1, 128, 0, stream>>>(pooled, cls_w, cls_b, out);
}

// Round 2
// 1114.146 us; speedup vs baseline: 1.8355x; 1.8355x over previous
//
#include <hip/hip_runtime.h>
#include <math.h>

#define DM 256      // D_MODEL
#define NL 4        // N_LAYERS
#define DI 512      // D_INNER
#define DS 16       // D_STATE
#define DC 4        // D_CONV
#define DR 16       // DT_RANK
#define NC 10       // NUM_CLASSES
#define NB 8        // B
#define LL 1024     // L
#define MR (NB*LL)  // 8192 rows
#define NCHUNK 32   // scan chunks
#define CLEN 32     // chunk length (NCHUNK*CLEN == LL)

__device__ __forceinline__ float silu_f(float x) {
    return x * (1.0f / (1.0f + __expf(-x)));
}

// h[m][d] = x[m] * w[d] + b[d]
__global__ void input_proj_kernel(const float* __restrict__ x, const float* __restrict__ w,
                                  const float* __restrict__ b, float* __restrict__ h) {
    int t = blockIdx.x * 256 + threadIdx.x;
    if (t >= MR * DM) return;
    int d = t & (DM - 1);
    int m = t >> 8;
    h[t] = x[m] * w[d] + b[d];
}

// one block (256 thr) per row of 256
__global__ __launch_bounds__(256) void layernorm_kernel(const float* __restrict__ in,
        const float* __restrict__ w, const float* __restrict__ b, float* __restrict__ out) {
    int row = blockIdx.x, t = threadIdx.x;
    float v = in[row * DM + t];
    float s = v, q = v * v;
#pragma unroll
    for (int o = 32; o >= 1; o >>= 1) { s += __shfl_xor(s, o); q += __shfl_xor(q, o); }
    __shared__ float red[8];
    int wid = t >> 6;
    if ((t & 63) == 0) { red[wid] = s; red[4 + wid] = q; }
    __syncthreads();
    s = red[0] + red[1] + red[2] + red[3];
    q = red[4] + red[5] + red[6] + red[7];
    float mu = s * (1.0f / DM);
    float var = q * (1.0f / DM) - mu * mu;
    float rs = rsqrtf(var + 1e-5f);
    out[row * DM + t] = (v - mu) * rs * w[t] + b[t];
}

// C[M,N] = A[M,K] @ W[N,K]^T (+bias) ; EPI==1: C += ...
template<int EPI>
__global__ __launch_bounds__(256) void gemm_kernel(
        const float* __restrict__ A, int lda,
        const float* __restrict__ W, const float* __restrict__ bias,
        float* __restrict__ C, int ldc, int N, int K) {
    __shared__ float As[16][68];
    __shared__ float Ws[16][68];
    int tid = threadIdx.x;
    int bm = blockIdx.x * 64, bn = blockIdx.y * 64;
    int tx = tid & 15, ty = tid >> 4;
    int lr = tid >> 2;            // load row 0..63
    int lk = (tid & 3) << 2;      // load k offset 0,4,8,12
    float acc[4][4] = {};
    for (int k0 = 0; k0 < K; k0 += 16) {
        float4 av = *reinterpret_cast<const float4*>(&A[(size_t)(bm + lr) * lda + k0 + lk]);
        float4 wv = make_float4(0.f, 0.f, 0.f, 0.f);
        if (bn + lr < N) wv = *reinterpret_cast<const float4*>(&W[(size_t)(bn + lr) * K + k0 + lk]);
        As[lk + 0][lr] = av.x; As[lk + 1][lr] = av.y; As[lk + 2][lr] = av.z; As[lk + 3][lr] = av.w;
        Ws[lk + 0][lr] = wv.x; Ws[lk + 1][lr] = wv.y; Ws[lk + 2][lr] = wv.z; Ws[lk + 3][lr] = wv.w;
        __syncthreads();
#pragma unroll
        for (int kk = 0; kk < 16; kk++) {
            float4 a4 = *reinterpret_cast<const float4*>(&As[kk][ty * 4]);
            float4 b4 = *reinterpret_cast<const float4*>(&Ws[kk][tx * 4]);
            acc[0][0] += a4.x * b4.x; acc[0][1] += a4.x * b4.y; acc[0][2] += a4.x * b4.z; acc[0][3] += a4.x * b4.w;
            acc[1][0] += a4.y * b4.x; acc[1][1] += a4.y * b4.y; acc[1][2] += a4.y * b4.z; acc[1][3] += a4.y * b4.w;
            acc[2][0] += a4.z * b4.x; acc[2][1] += a4.z * b4.y; acc[2][2] += a4.z * b4.z; acc[2][3] += a4.z * b4.w;
            acc[3][0] += a4.w * b4.x; acc[3][1] += a4.w * b4.y; acc[3][2] += a4.w * b4.z; acc[3][3] += a4.w * b4.w;
        }
        __syncthreads();
    }
    int cm = bm + ty * 4, cn = bn + tx * 4;
#pragma unroll
    for (int i = 0; i < 4; i++) {
#pragma unroll
        for (int j = 0; j < 4; j++) {
            int col = cn + j;
            if (col < N) {
                float v = acc[i][j];
                if (bias) v += bias[col];
                if (EPI == 1) v += C[(size_t)(cm + i) * ldc + col];
                C[(size_t)(cm + i) * ldc + col] = v;
            }
        }
    }
}

// u[m][d] = silu( conv ), u_pre = xz cols 0..511 (ld 1024)
__global__ void conv_silu_kernel(const float* __restrict__ xz, const float* __restrict__ cw,
                                 const float* __restrict__ cb, float* __restrict__ u) {
    int t = blockIdx.x * 256 + threadIdx.x;
    if (t >= MR * DI) return;
    int d = t & (DI - 1);
    int m = t >> 9;
    int l = m & (LL - 1);
    const float4 w4 = *reinterpret_cast<const float4*>(&cw[d * 4]);
    float acc = cb[d] + w4.w * xz[(size_t)m * 1024 + d];
    if (l >= 1) acc += w4.z * xz[(size_t)(m - 1) * 1024 + d];
    if (l >= 2) acc += w4.y * xz[(size_t)(m - 2) * 1024 + d];
    if (l >= 3) acc += w4.x * xz[(size_t)(m - 3) * 1024 + d];
    u[t] = silu_f(acc);
}

// delta[m][d] = softplus( sum_k x_dbl[m][k] * dtw[d][k] + dtb[d] )
__global__ __launch_bounds__(256) void dtproj_kernel(const float* __restrict__ x_dbl,
        const float* __restrict__ dtw, const float* __restrict__ dtb, float* __restrict__ delta) {
    int m = blockIdx.x, t = threadIdx.x;
    __shared__ float dts[DR];
    if (t < DR) dts[t] = x_dbl[(size_t)m * 48 + t];
    __syncthreads();
#pragma unroll
    for (int p = 0; p < 2; p++) {
        int d = t + p * 256;
        float acc = dtb[d];
#pragma unroll
        for (int k = 0; k < DR; k++) acc += dtw[d * DR + k] * dts[k];
        float sp = (acc > 20.0f) ? acc : log1pf(expf(acc));
        delta[(size_t)m * DI + d] = sp;
    }
}

// ---------------- chunked parallel scan ----------------
// Phase 1: per (b,chunk,d) thread, 16 states in registers.
// P[n] = prod dA, S[n] = chunk state from h=0. Layout [b][c][d][n].
__global__ __launch_bounds__(256) void scan_phase1_kernel(
        const float* __restrict__ u, const float* __restrict__ delta,
        const float* __restrict__ x_dbl, const float* __restrict__ A_log,
        float* __restrict__ Pbuf, float* __restrict__ Sbuf) {
    int gid = blockIdx.x * 256 + threadIdx.x;
    int d = gid & (DI - 1);
    int c = (gid >> 9) & (NCHUNK - 1);
    int b = gid >> 14;
    float Aval[DS], h[DS], P[DS];
#pragma unroll
    for (int q = 0; q < 4; q++) {
        float4 a4 = *reinterpret_cast<const float4*>(&A_log[d * DS + q * 4]);
        Aval[q * 4 + 0] = -__expf(a4.x); Aval[q * 4 + 1] = -__expf(a4.y);
        Aval[q * 4 + 2] = -__expf(a4.z); Aval[q * 4 + 3] = -__expf(a4.w);
    }
#pragma unroll
    for (int n = 0; n < DS; n++) { h[n] = 0.f; P[n] = 1.f; }
    int m0 = b * LL + c * CLEN;
    for (int t = 0; t < CLEN; t++) {
        int m = m0 + t;
        float dv = delta[(size_t)m * DI + d];
        float uv = u[(size_t)m * DI + d];
        float du = dv * uv;
        const float* xb = &x_dbl[(size_t)m * 48 + 16];
#pragma unroll
        for (int q = 0; q < 4; q++) {
            float4 B4 = *reinterpret_cast<const float4*>(&xb[q * 4]);
            float Bn[4] = {B4.x, B4.y, B4.z, B4.w};
#pragma unroll
            for (int j = 0; j < 4; j++) {
                int n = q * 4 + j;
                float dA = __expf(dv * Aval[n]);
                h[n] = dA * h[n] + du * Bn[j];
                P[n] *= dA;
            }
        }
    }
    size_t base = ((size_t)((b * NCHUNK + c) * DI + d)) * DS;
#pragma unroll
    for (int q = 0; q < 4; q++) {
        *reinterpret_cast<float4*>(&Pbuf[base + q * 4]) = make_float4(P[q*4], P[q*4+1], P[q*4+2], P[q*4+3]);
        *reinterpret_cast<float4*>(&Sbuf[base + q * 4]) = make_float4(h[q*4], h[q*4+1], h[q*4+2], h[q*4+3]);
    }
}

// Phase 2: per (b,d,n) thread, exclusive scan over chunks. Sbuf[c] is
// overwritten with hinit[c] (state BEFORE chunk c).
__global__ __launch_bounds__(256) void scan_phase2_kernel(
        const float* __restrict__ Pbuf, float* __restrict__ Sbuf) {
    int gid = blockIdx.x * 256 + threadIdx.x;   // n fastest, then d, then b
    int dn = gid & (DI * DS - 1);
    int b = gid >> 13;
    size_t idx0 = (size_t)b * NCHUNK * DI * DS + dn;
    const size_t stride = (size_t)DI * DS;
    float h = 0.f;
    float Pc = Pbuf[idx0], Sc = Sbuf[idx0];
    for (int c = 0; c < NCHUNK; c++) {
        size_t idx = idx0 + (size_t)c * stride;
        float Pn = 0.f, Sn = 0.f;
        if (c + 1 < NCHUNK) {
            Pn = Pbuf[idx + stride];
            Sn = Sbuf[idx + stride];
        }
        Sbuf[idx] = h;            // hinit for chunk c
        h = Pc * h + Sc;
        Pc = Pn; Sc = Sn;
    }
}

// Phase 3: replay chunk from hinit, produce y.
__global__ __launch_bounds__(256) void scan_phase3_kernel(
        const float* __restrict__ u, const float* __restrict__ delta,
        const float* __restrict__ x_dbl, const float* __restrict__ A_log,
        const float* __restrict__ Dp, const float* __restrict__ Sbuf,
        float* __restrict__ y) {
    int gid = blockIdx.x * 256 + threadIdx.x;
    int d = gid & (DI - 1);
    int c = (gid >> 9) & (NCHUNK - 1);
    int b = gid >> 14;
    float Aval[DS], h[DS];
#pragma unroll
    for (int q = 0; q < 4; q++) {
        float4 a4 = *reinterpret_cast<const float4*>(&A_log[d * DS + q * 4]);
        Aval[q * 4 + 0] = -__expf(a4.x); Aval[q * 4 + 1] = -__expf(a4.y);
        Aval[q * 4 + 2] = -__expf(a4.z); Aval[q * 4 + 3] = -__expf(a4.w);
    }
    size_t base = ((size_t)((b * NCHUNK + c) * DI + d)) * DS;
#pragma unroll
    for (int q = 0; q < 4; q++) {
        float4 h4 = *reinterpret_cast<const float4*>(&Sbuf[base + q * 4]);
        h[q * 4 + 0] = h4.x; h[q * 4 + 1] = h4.y; h[q * 4 + 2] = h4.z; h[q * 4 + 3] = h4.w;
    }
    float Dval = Dp[d];
    int m0 = b * LL + c * CLEN;
    for (int t = 0; t < CLEN; t++) {
        int m = m0 + t;
        float dv = delta[(size_t)m * DI + d];
        float uv = u[(size_t)m * DI + d];
        float du = dv * uv;
        const float* xb = &x_dbl[(size_t)m * 48 + 16];
        float acc = Dval * uv;
#pragma unroll
        for (int q = 0; q < 4; q++) {
            float4 B4 = *reinterpret_cast<const float4*>(&xb[q * 4]);
            float4 C4 = *reinterpret_cast<const float4*>(&xb[16 + q * 4]);
            float Bn[4] = {B4.x, B4.y, B4.z, B4.w};
            float Cn[4] = {C4.x, C4.y, C4.z, C4.w};
#pragma unroll
            for (int j = 0; j < 4; j++) {
                int n = q * 4 + j;
                float dA = __expf(dv * Aval[n]);
                h[n] = dA * h[n] + du * Bn[j];
                acc += h[n] * Cn[j];
            }
        }
        y[(size_t)m * DI + d] = acc;
    }
}

// y[m][d] *= silu(res[m][d]),  res = xz cols 512..1023
__global__ void gate_kernel(float* __restrict__ y, const float* __restrict__ xz) {
    int t = blockIdx.x * 256 + threadIdx.x;
    if (t >= MR * DI) return;
    int d = t & (DI - 1);
    int m = t >> 9;
    float r = xz[(size_t)m * 1024 + 512 + d];
    y[t] *= silu_f(r);
}

// pooled[b][dm] = mean_l ln[b*L+l][dm]
__global__ void pool_kernel(const float* __restrict__ ln, float* __restrict__ pooled) {
    int t = blockIdx.x * 256 + threadIdx.x;
    if (t >= NB * DM) return;
    int b = t >> 8, dmn = t & 255;
    float s = 0.f;
    for (int l = 0; l < LL; l++) s += ln[(size_t)(b * LL + l) * DM + dmn];
    pooled[t] = s * (1.0f / LL);
}

__global__ void cls_kernel(const float* __restrict__ pooled, const float* __restrict__ cw,
                           const float* __restrict__ cb, float* __restrict__ out) {
    int t = threadIdx.x;
    if (t >= NB * NC) return;
    int b = t / NC, c = t % NC;
    float s = cb[c];
    for (int k = 0; k < DM; k++) s += pooled[b * DM + k] * cw[c * DM + k];
    out[t] = s;
}

extern "C" void kernel_launch(void* const* d_in, const int* in_sizes, int n_in,
                              void* d_out, int out_size, void* d_ws, size_t ws_size,
                              hipStream_t stream) {
    const float* x       = (const float*)d_in[0];
    const float* input_w = (const float*)d_in[1];
    const float* input_b = (const float*)d_in[2];
    const float* ln_w    = (const float*)d_in[3];
    const float* ln_b    = (const float*)d_in[4];
    const float* ipw     = (const float*)d_in[5];
    const float* ipb     = (const float*)d_in[6];
    const float* cw      = (const float*)d_in[7];
    const float* cb      = (const float*)d_in[8];
    const float* xpw     = (const float*)d_in[9];
    const float* dtw     = (const float*)d_in[10];
    const float* dtb     = (const float*)d_in[11];
    const float* A_log   = (const float*)d_in[12];
    const float* Dp      = (const float*)d_in[13];
    const float* opw     = (const float*)d_in[14];
    const float* opb     = (const float*)d_in[15];
    const float* norm_w  = (const float*)d_in[16];
    const float* norm_b  = (const float*)d_in[17];
    const float* cls_w   = (const float*)d_in[18];
    const float* cls_b   = (const float*)d_in[19];
    float* out = (float*)d_out;
    float* ws = (float*)d_ws;

    float* hres   = ws;                           // MR*DM
    float* xz     = hres + (size_t)MR * DM;       // MR*1024
    float* u      = xz + (size_t)MR * 2 * DI;     // MR*DI
    float* delta  = u + (size_t)MR * DI;          // MR*DI
    float* ybuf   = delta + (size_t)MR * DI;      // MR*DI (also LN buffer)
    float* x_dbl  = ybuf + (size_t)MR * DI;       // MR*48
    float* pooled = x_dbl + (size_t)MR * 48;      // NB*DM
    float* Pbuf   = pooled + NB * DM;             // NB*NCHUNK*DI*DS
    float* Sbuf   = Pbuf + (size_t)NB * NCHUNK * DI * DS;

    input_proj_kernel<<<MR * DM / 256, 256, 0, stream>>>(x, input_w, input_b, hres);

    for (int i = 0; i < NL; i++) {
        layernorm_kernel<<<MR, 256, 0, stream>>>(hres, ln_w + i * DM, ln_b + i * DM, ybuf);
        gemm_kernel<0><<<dim3(MR / 64, (2 * DI) / 64), 256, 0, stream>>>(
            ybuf, DM, ipw + (size_t)i * 2 * DI * DM, ipb + i * 2 * DI, xz, 2 * DI, 2 * DI, DM);
        conv_silu_kernel<<<MR * DI / 256, 256, 0, stream>>>(xz, cw + i * DI * DC, cb + i * DI, u);
        gemm_kernel<0><<<dim3(MR / 64, 1), 256, 0, stream>>>(
            u, DI, xpw + (size_t)i * 48 * DI, nullptr, x_dbl, 48, 48, DI);
        dtproj_kernel<<<MR, 256, 0, stream>>>(x_dbl, dtw + i * DI * DR, dtb + i * DI, delta);
        scan_phase1_kernel<<<NB * NCHUNK * DI / 256, 256, 0, stream>>>(
            u, delta, x_dbl, A_log + i * DI * DS, Pbuf, Sbuf);
        scan_phase2_kernel<<<NB * DI * DS / 256, 256, 0, stream>>>(Pbuf, Sbuf);
        scan_phase3_kernel<<<NB * NCHUNK * DI / 256, 256, 0, stream>>>(
            u, delta, x_dbl, A_log + i * DI * DS, Dp + i * DI, Sbuf, ybuf);
        gate_kernel<<<MR * DI / 256, 256, 0, stream>>>(ybuf, xz);
        gemm_kernel<1><<<dim3(MR / 64, DM / 64), 256, 0, stream>>>(
            ybuf, DI, opw + (size_t)i * DM * DI, opb + i * DM, hres, DM, DM, DI);
    }

    layernorm_kernel<<<MR, 256, 0, stream>>>(hres, norm_w, norm_b, ybuf);
    pool_kernel<<<NB * DM / 256, 256, 0, stream>>>(ybuf, pooled);
    cls_kernel<<<1, 128, 0, stream>>>(pooled, cls_w, cls_b, out);
}

// Round 3
// 667.277 us; speedup vs baseline: 3.0647x; 1.6697x over previous
//
#include <hip/hip_runtime.h>
#include <hip/hip_bf16.h>
#include <math.h>

#define DM 256      // D_MODEL
#define NL 4        // N_LAYERS
#define DI 512      // D_INNER
#define DS 16       // D_STATE
#define DC 4        // D_CONV
#define DR 16       // DT_RANK
#define NC 10       // NUM_CLASSES
#define NB 8        // B
#define LL 1024     // L
#define MR (NB*LL)  // 8192 rows
#define NCHUNK 32
#define CLEN 32

typedef __attribute__((ext_vector_type(4))) float f32x4;
typedef __attribute__((ext_vector_type(8))) short short8;

__device__ __forceinline__ float silu_f(float x) {
    return x * (1.0f / (1.0f + __expf(-x)));
}
__device__ __forceinline__ float bf2f(ushort v) {
    union { unsigned u; float f; } c; c.u = ((unsigned)v) << 16; return c.f;
}
__device__ __forceinline__ ushort f2bf(float f) {   // round-to-nearest-even
    union { float f; unsigned u; } c; c.f = f;
    unsigned lsb = (c.u >> 16) & 1;
    return (ushort)((c.u + 0x7fffu + lsb) >> 16);
}
__device__ __forceinline__ void g2lds16(const void* g, void* l) {
    __builtin_amdgcn_global_load_lds((const __attribute__((address_space(1))) void*)g,
                                     (__attribute__((address_space(3))) void*)l, 16, 0, 0);
}

// ---- weight fp32 -> bf16 conversion (x_proj padded 48 -> 64 rows) ----
#define IPW_N (NL*2*DI*DM)   // 1048576
#define XPW_N (NL*64*DI)     // 131072 (padded)
#define OPW_N (NL*DM*DI)     // 524288
__global__ __launch_bounds__(256) void convert_weights_kernel(
        const float* __restrict__ ipw, const float* __restrict__ xpw,
        const float* __restrict__ opw,
        ushort* __restrict__ ipw_b, ushort* __restrict__ xpw_b, ushort* __restrict__ opw_b) {
    int t = blockIdx.x * 256 + threadIdx.x;
    if (t < IPW_N) { ipw_b[t] = f2bf(ipw[t]); return; }
    t -= IPW_N;
    if (t < XPW_N) {
        int l = t >> 15, r = (t >> 9) & 63, k = t & 511;
        xpw_b[t] = (r < 48) ? f2bf(xpw[((size_t)l * 48 + r) * DI + k]) : (ushort)0;
        return;
    }
    t -= XPW_N;
    if (t < OPW_N) opw_b[t] = f2bf(opw[t]);
}

// h[m][d] = x[m] * w[d] + b[d]  (fp32 residual stream init)
__global__ void input_proj_kernel(const float* __restrict__ x, const float* __restrict__ w,
                                  const float* __restrict__ b, float* __restrict__ h) {
    int t = blockIdx.x * 256 + threadIdx.x;
    if (t >= MR * DM) return;
    int d = t & (DM - 1);
    int m = t >> 8;
    h[t] = x[m] * w[d] + b[d];
}

// layernorm over 256 cols, bf16 output
__global__ __launch_bounds__(256) void layernorm_bf16_kernel(const float* __restrict__ in,
        const float* __restrict__ w, const float* __restrict__ b, ushort* __restrict__ out) {
    int row = blockIdx.x, t = threadIdx.x;
    float v = in[row * DM + t];
    float s = v, q = v * v;
#pragma unroll
    for (int o = 32; o >= 1; o >>= 1) { s += __shfl_xor(s, o); q += __shfl_xor(q, o); }
    __shared__ float red[8];
    int wid = t >> 6;
    if ((t & 63) == 0) { red[wid] = s; red[4 + wid] = q; }
    __syncthreads();
    s = red[0] + red[1] + red[2] + red[3];
    q = red[4] + red[5] + red[6] + red[7];
    float mu = s * (1.0f / DM);
    float var = q * (1.0f / DM) - mu * mu;
    float rs = rsqrtf(var + 1e-5f);
    out[row * DM + t] = f2bf((v - mu) * rs * w[t] + b[t]);
}

// ---- bf16 MFMA GEMM: C[M,N] = A[M,K] @ W[N,K]^T ----
// MODE 0: bf16 out + bias; MODE 1: f32 out; MODE 2: f32 out += acc + bias
// BK=64. LDS tiles row-major [row][64] bf16 (128 B/row) with XOR swizzle
// (bits 4-6 ^= row&7) applied on BOTH the staging source and the ds_read.
template<int BM, int BN, int WM, int WN, int MODE>
__global__ __launch_bounds__(256) void mfma_gemm_kernel(
        const ushort* __restrict__ A, int lda,
        const ushort* __restrict__ W,
        const float* __restrict__ bias,
        ushort* __restrict__ Cb, float* __restrict__ Cf, int ldc, int K) {
    constexpr int FM = BM / WM / 16;
    constexpr int FN = BN / WN / 16;
    __shared__ __align__(16) char smem[(BM + BN) * 128];
    const int tid = threadIdx.x;
    const int l = tid & 63, w = tid >> 6;
    const int wr = w / WN, wc = w % WN;
    const int bm = blockIdx.x * BM, bn = blockIdx.y * BN;
    const int ldw = K;

    f32x4 acc[FM][FN] = {};

    for (int k0 = 0; k0 < K; k0 += 64) {
#pragma unroll
        for (int i = 0; i < (BM * 128 / 16) / 256; i++) {
            int lin = (i * 256 + tid) * 16;
            int q = lin ^ (((lin >> 7) & 7) << 4);
            g2lds16(A + (size_t)(bm + (q >> 7)) * lda + k0 + ((q & 127) >> 1), smem + lin);
        }
#pragma unroll
        for (int i = 0; i < (BN * 128 / 16) / 256; i++) {
            int lin = (i * 256 + tid) * 16;
            int q = lin ^ (((lin >> 7) & 7) << 4);
            g2lds16(W + (size_t)(bn + (q >> 7)) * ldw + k0 + ((q & 127) >> 1),
                    smem + BM * 128 + lin);
        }
        __syncthreads();
        const int rl = l & 15;
        const int kb0 = ((l >> 4) << 3) * 2;
#pragma unroll
        for (int kk = 0; kk < 2; kk++) {
            short8 af[FM], bfr[FN];
#pragma unroll
            for (int m = 0; m < FM; m++) {
                int off = (wr * (BM / WM) + m * 16 + rl) * 128 + kk * 64 + kb0;
                off ^= ((off >> 7) & 7) << 4;
                af[m] = *(const short8*)(smem + off);
            }
#pragma unroll
            for (int n = 0; n < FN; n++) {
                int off = (wc * (BN / WN) + n * 16 + rl) * 128 + kk * 64 + kb0;
                off ^= ((off >> 7) & 7) << 4;
                bfr[n] = *(const short8*)(smem + BM * 128 + off);
            }
#pragma unroll
            for (int m = 0; m < FM; m++)
#pragma unroll
                for (int n = 0; n < FN; n++)
                    acc[m][n] = __builtin_amdgcn_mfma_f32_16x16x32_bf16(
                        af[m], bfr[n], acc[m][n], 0, 0, 0);
        }
        __syncthreads();
    }

    const int row0 = bm + wr * (BM / WM) + ((l >> 4) << 2);
    const int col0 = bn + wc * (BN / WN) + (l & 15);
#pragma unroll
    for (int m = 0; m < FM; m++) {
#pragma unroll
        for (int n = 0; n < FN; n++) {
            int col = col0 + n * 16;
            float bv = (MODE == 1) ? 0.f : bias[col];
#pragma unroll
            for (int r = 0; r < 4; r++) {
                size_t idx = (size_t)(row0 + m * 16 + r) * ldc + col;
                float v = acc[m][n][r];
                if (MODE == 0) Cb[idx] = f2bf(v + bv);
                else if (MODE == 1) Cf[idx] = v;
                else Cf[idx] += v + bv;
            }
        }
    }
}

// depthwise causal conv (K=4) + SiLU; xz bf16 (ld 1024, cols 0..511) -> u bf16
__global__ __launch_bounds__(256) void conv_silu_kernel(const ushort* __restrict__ xz,
        const float* __restrict__ cw, const float* __restrict__ cb, ushort* __restrict__ u) {
    int t = blockIdx.x * 256 + threadIdx.x;   // MR*DI/8 threads
    int d8 = (t & 63) << 3;
    int m = t >> 6;
    int l = m & (LL - 1);
    const short8 zr = {0, 0, 0, 0, 0, 0, 0, 0};
    const size_t base = (size_t)m * 1024 + d8;
    short8 r3 = *(const short8*)(xz + base);
    short8 r2 = (l >= 1) ? *(const short8*)(xz + base - 1024) : zr;
    short8 r1 = (l >= 2) ? *(const short8*)(xz + base - 2048) : zr;
    short8 r0 = (l >= 3) ? *(const short8*)(xz + base - 3072) : zr;
    short8 o;
#pragma unroll
    for (int j = 0; j < 8; j++) {
        int d = d8 + j;
        float4 w4 = *reinterpret_cast<const float4*>(&cw[d * 4]);
        float a = cb[d] + w4.w * bf2f((ushort)r3[j]);
        a += w4.z * bf2f((ushort)r2[j]);
        a += w4.y * bf2f((ushort)r1[j]);
        a += w4.x * bf2f((ushort)r0[j]);
        o[j] = (short)f2bf(silu_f(a));
    }
    *(short8*)(u + (size_t)m * DI + d8) = o;
}

// delta[m][d] = softplus( x_dbl[m][0..15] . dtw[d][:] + dtb[d] ), x_dbl ld 64
__global__ __launch_bounds__(256) void dtproj_kernel(const float* __restrict__ x_dbl,
        const float* __restrict__ dtw, const float* __restrict__ dtb, float* __restrict__ delta) {
    int m = blockIdx.x, t = threadIdx.x;
    __shared__ float dts[DR];
    if (t < DR) dts[t] = x_dbl[(size_t)m * 64 + t];
    __syncthreads();
#pragma unroll
    for (int p = 0; p < 2; p++) {
        int d = t + p * 256;
        float acc = dtb[d];
#pragma unroll
        for (int k = 0; k < DR; k++) acc += dtw[d * DR + k] * dts[k];
        float sp = (acc > 20.0f) ? acc : log1pf(expf(acc));
        delta[(size_t)m * DI + d] = sp;
    }
}

// ---- chunked parallel scan; u bf16, x_dbl f32 ld 64 ----
__global__ __launch_bounds__(256) void scan_phase1_kernel(
        const ushort* __restrict__ u, const float* __restrict__ delta,
        const float* __restrict__ x_dbl, const float* __restrict__ A_log,
        float* __restrict__ Pbuf, float* __restrict__ Sbuf) {
    int gid = blockIdx.x * 256 + threadIdx.x;
    int d = gid & (DI - 1);
    int c = (gid >> 9) & (NCHUNK - 1);
    int b = gid >> 14;
    float Aval[DS], h[DS], P[DS];
#pragma unroll
    for (int q = 0; q < 4; q++) {
        float4 a4 = *reinterpret_cast<const float4*>(&A_log[d * DS + q * 4]);
        Aval[q * 4 + 0] = -__expf(a4.x); Aval[q * 4 + 1] = -__expf(a4.y);
        Aval[q * 4 + 2] = -__expf(a4.z); Aval[q * 4 + 3] = -__expf(a4.w);
    }
#pragma unroll
    for (int n = 0; n < DS; n++) { h[n] = 0.f; P[n] = 1.f; }
    int m0 = b * LL + c * CLEN;
    for (int t = 0; t < CLEN; t++) {
        int m = m0 + t;
        float dv = delta[(size_t)m * DI + d];
        float uv = bf2f(u[(size_t)m * DI + d]);
        float du = dv * uv;
        const float* xb = &x_dbl[(size_t)m * 64 + 16];
#pragma unroll
        for (int q = 0; q < 4; q++) {
            float4 B4 = *reinterpret_cast<const float4*>(&xb[q * 4]);
            float Bn[4] = {B4.x, B4.y, B4.z, B4.w};
#pragma unroll
            for (int j = 0; j < 4; j++) {
                int n = q * 4 + j;
                float dA = __expf(dv * Aval[n]);
                h[n] = dA * h[n] + du * Bn[j];
                P[n] *= dA;
            }
        }
    }
    size_t base = ((size_t)((b * NCHUNK + c) * DI + d)) * DS;
#pragma unroll
    for (int q = 0; q < 4; q++) {
        *reinterpret_cast<float4*>(&Pbuf[base + q * 4]) = make_float4(P[q*4], P[q*4+1], P[q*4+2], P[q*4+3]);
        *reinterpret_cast<float4*>(&Sbuf[base + q * 4]) = make_float4(h[q*4], h[q*4+1], h[q*4+2], h[q*4+3]);
    }
}

__global__ __launch_bounds__(256) void scan_phase2_kernel(
        const float* __restrict__ Pbuf, float* __restrict__ Sbuf) {
    int gid = blockIdx.x * 256 + threadIdx.x;
    int dn = gid & (DI * DS - 1);
    int b = gid >> 13;
    size_t idx0 = (size_t)b * NCHUNK * DI * DS + dn;
    const size_t stride = (size_t)DI * DS;
    float h = 0.f;
    float Pc = Pbuf[idx0], Sc = Sbuf[idx0];
    for (int c = 0; c < NCHUNK; c++) {
        size_t idx = idx0 + (size_t)c * stride;
        float Pn = 0.f, Sn = 0.f;
        if (c + 1 < NCHUNK) { Pn = Pbuf[idx + stride]; Sn = Sbuf[idx + stride]; }
        Sbuf[idx] = h;
        h = Pc * h + Sc;
        Pc = Pn; Sc = Sn;
    }
}

// phase3 + fused gate: y = (scan_y) * silu(res), written bf16
__global__ __launch_bounds__(256) void scan_phase3_kernel(
        const ushort* __restrict__ u, const float* __restrict__ delta,
        const float* __restrict__ x_dbl, const float* __restrict__ A_log,
        const float* __restrict__ Dp, const float* __restrict__ Sbuf,
        const ushort* __restrict__ xz, ushort* __restrict__ y) {
    int gid = blockIdx.x * 256 + threadIdx.x;
    int d = gid & (DI - 1);
    int c = (gid >> 9) & (NCHUNK - 1);
    int b = gid >> 14;
    float Aval[DS], h[DS];
#pragma unroll
    for (int q = 0; q < 4; q++) {
        float4 a4 = *reinterpret_cast<const float4*>(&A_log[d * DS + q * 4]);
        Aval[q * 4 + 0] = -__expf(a4.x); Aval[q * 4 + 1] = -__expf(a4.y);
        Aval[q * 4 + 2] = -__expf(a4.z); Aval[q * 4 + 3] = -__expf(a4.w);
    }
    size_t base = ((size_t)((b * NCHUNK + c) * DI + d)) * DS;
#pragma unroll
    for (int q = 0; q < 4; q++) {
        float4 h4 = *reinterpret_cast<const float4*>(&Sbuf[base + q * 4]);
        h[q * 4 + 0] = h4.x; h[q * 4 + 1] = h4.y; h[q * 4 + 2] = h4.z; h[q * 4 + 3] = h4.w;
    }
    float Dval = Dp[d];
    int m0 = b * LL + c * CLEN;
    for (int t = 0; t < CLEN; t++) {
        int m = m0 + t;
        float dv = delta[(size_t)m * DI + d];
        float uv = bf2f(u[(size_t)m * DI + d]);
        float du = dv * uv;
        const float* xb = &x_dbl[(size_t)m * 64 + 16];
        float acc = Dval * uv;
#pragma unroll
        for (int q = 0; q < 4; q++) {
            float4 B4 = *reinterpret_cast<const float4*>(&xb[q * 4]);
            float4 C4 = *reinterpret_cast<const float4*>(&xb[16 + q * 4]);
            float Bn[4] = {B4.x, B4.y, B4.z, B4.w};
            float Cn[4] = {C4.x, C4.y, C4.z, C4.w};
#pragma unroll
            for (int j = 0; j < 4; j++) {
                int n = q * 4 + j;
                float dA = __expf(dv * Aval[n]);
                h[n] = dA * h[n] + du * Bn[j];
                acc += h[n] * Cn[j];
            }
        }
        float res = bf2f(xz[(size_t)m * 1024 + 512 + d]);
        y[(size_t)m * DI + d] = f2bf(acc * silu_f(res));
    }
}

// pooled[b][dm] = mean_l ln_bf16[b*L+l][dm]
__global__ void pool_kernel(const ushort* __restrict__ ln, float* __restrict__ pooled) {
    int t = blockIdx.x * 256 + threadIdx.x;
    if (t >= NB * DM) return;
    int b = t >> 8, dmn = t & 255;
    float s = 0.f;
    for (int l = 0; l < LL; l++) s += bf2f(ln[(size_t)(b * LL + l) * DM + dmn]);
    pooled[t] = s * (1.0f / LL);
}

__global__ void cls_kernel(const float* __restrict__ pooled, const float* __restrict__ cw,
                           const float* __restrict__ cb, float* __restrict__ out) {
    int t = threadIdx.x;
    if (t >= NB * NC) return;
    int b = t / NC, c = t % NC;
    float s = cb[c];
    for (int k = 0; k < DM; k++) s += pooled[b * DM + k] * cw[c * DM + k];
    out[t] = s;
}

extern "C" void kernel_launch(void* const* d_in, const int* in_sizes, int n_in,
                              void* d_out, int out_size, void* d_ws, size_t ws_size,
                              hipStream_t stream) {
    const float* x       = (const float*)d_in[0];
    const float* input_w = (const float*)d_in[1];
    const float* input_b = (const float*)d_in[2];
    const float* ln_w    = (const float*)d_in[3];
    const float* ln_b    = (const float*)d_in[4];
    const float* ipw     = (const float*)d_in[5];
    const float* ipb     = (const float*)d_in[6];
    const float* cw      = (const float*)d_in[7];
    const float* cb      = (const float*)d_in[8];
    const float* xpw     = (const float*)d_in[9];
    const float* dtw     = (const float*)d_in[10];
    const float* dtb     = (const float*)d_in[11];
    const float* A_log   = (const float*)d_in[12];
    const float* Dp      = (const float*)d_in[13];
    const float* opw     = (const float*)d_in[14];
    const float* opb     = (const float*)d_in[15];
    const float* norm_w  = (const float*)d_in[16];
    const float* norm_b  = (const float*)d_in[17];
    const float* cls_w   = (const float*)d_in[18];
    const float* cls_b   = (const float*)d_in[19];
    float* out = (float*)d_out;
    float* ws = (float*)d_ws;

    float*  hres  = ws;                               // MR*DM f32
    ushort* xz    = (ushort*)(hres + (size_t)MR * DM);// MR*1024 bf16
    ushort* ub    = xz + (size_t)MR * 1024;           // MR*DI bf16
    float*  delta = (float*)(ub + (size_t)MR * DI);   // MR*DI f32
    float*  x_dbl = delta + (size_t)MR * DI;          // MR*64 f32
    float*  Pbuf  = x_dbl + (size_t)MR * 64;          // NB*NCHUNK*DI*DS f32
    float*  Sbuf  = Pbuf + (size_t)NB * NCHUNK * DI * DS;
    float*  pooled= Sbuf + (size_t)NB * NCHUNK * DI * DS;  // NB*DM
    ushort* ygate = (ushort*)(pooled + NB * DM);      // MR*DI bf16
    ushort* hln   = ygate + (size_t)MR * DI;          // MR*DM bf16
    ushort* ipw_b = hln + (size_t)MR * DM;            // IPW_N
    ushort* xpw_b = ipw_b + IPW_N;                    // XPW_N
    ushort* opw_b = xpw_b + XPW_N;                    // OPW_N

    convert_weights_kernel<<<(IPW_N + XPW_N + OPW_N) / 256, 256, 0, stream>>>(
        ipw, xpw, opw, ipw_b, xpw_b, opw_b);
    input_proj_kernel<<<MR * DM / 256, 256, 0, stream>>>(x, input_w, input_b, hres);

    for (int i = 0; i < NL; i++) {
        layernorm_bf16_kernel<<<MR, 256, 0, stream>>>(hres, ln_w + i * DM, ln_b + i * DM, hln);
        mfma_gemm_kernel<128, 128, 2, 2, 0><<<dim3(MR / 128, 1024 / 128), 256, 0, stream>>>(
            hln, DM, ipw_b + (size_t)i * 2 * DI * DM, ipb + (size_t)i * 2 * DI,
            xz, nullptr, 1024, DM);
        conv_silu_kernel<<<MR * DI / 8 / 256, 256, 0, stream>>>(xz, cw + i * DI * DC, cb + i * DI, ub);
        mfma_gemm_kernel<64, 64, 4, 1, 1><<<dim3(MR / 64, 1), 256, 0, stream>>>(
            ub, DI, xpw_b + (size_t)i * 64 * DI, nullptr, nullptr, x_dbl, 64, DI);
        dtproj_kernel<<<MR, 256, 0, stream>>>(x_dbl, dtw + i * DI * DR, dtb + i * DI, delta);
        scan_phase1_kernel<<<NB * NCHUNK * DI / 256, 256, 0, stream>>>(
            ub, delta, x_dbl, A_log + i * DI * DS, Pbuf, Sbuf);
        scan_phase2_kernel<<<NB * DI * DS / 256, 256, 0, stream>>>(Pbuf, Sbuf);
        scan_phase3_kernel<<<NB * NCHUNK * DI / 256, 256, 0, stream>>>(
            ub, delta, x_dbl, A_log + i * DI * DS, Dp + i * DI, Sbuf, xz, ygate);
        mfma_gemm_kernel<64, 128, 2, 2, 2><<<dim3(MR / 64, DM / 128), 256, 0, stream>>>(
            ygate, DI, opw_b + (size_t)i * DM * DI, opb + (size_t)i * DM,
            nullptr, hres, DM, DI);
    }

    layernorm_bf16_kernel<<<MR, 256, 0, stream>>>(hres, norm_w, norm_b, hln);
    pool_kernel<<<NB * DM / 256, 256, 0, stream>>>(hln, pooled);
    cls_kernel<<<1, 128, 0, stream>>>(pooled, cls_w, cls_b, out);
}

// Round 4
// 513.903 us; speedup vs baseline: 3.9794x; 1.2984x over previous
//
#include <hip/hip_runtime.h>
#include <hip/hip_bf16.h>
#include <math.h>

#define DM 256      // D_MODEL
#define NL 4        // N_LAYERS
#define DI 512      // D_INNER
#define DS 16       // D_STATE
#define DC 4        // D_CONV
#define DR 16       // DT_RANK
#define NC 10       // NUM_CLASSES
#define NB 8        // B
#define LL 1024     // L
#define MR (NB*LL)  // 8192 rows
#define NCHUNK 64
#define CLEN 16

typedef __attribute__((ext_vector_type(4))) float f32x4;
typedef __attribute__((ext_vector_type(8))) short short8;

__device__ __forceinline__ float silu_f(float x) {
    return x * (1.0f / (1.0f + __expf(-x)));
}
__device__ __forceinline__ float bf2f(ushort v) {
    union { unsigned u; float f; } c; c.u = ((unsigned)v) << 16; return c.f;
}
__device__ __forceinline__ ushort f2bf(float f) {   // round-to-nearest-even
    union { float f; unsigned u; } c; c.f = f;
    unsigned lsb = (c.u >> 16) & 1;
    return (ushort)((c.u + 0x7fffu + lsb) >> 16);
}
__device__ __forceinline__ void g2lds16(const void* g, void* l) {
    __builtin_amdgcn_global_load_lds((const __attribute__((address_space(1))) void*)g,
                                     (__attribute__((address_space(3))) void*)l, 16, 0, 0);
}

// ---- weight fp32 -> bf16 conversion (x_proj padded 48 -> 64 rows) ----
#define IPW_N (NL*2*DI*DM)   // 1048576
#define XPW_N (NL*64*DI)     // 131072 (padded)
#define OPW_N (NL*DM*DI)     // 524288
__global__ __launch_bounds__(256) void convert_weights_kernel(
        const float* __restrict__ ipw, const float* __restrict__ xpw,
        const float* __restrict__ opw,
        ushort* __restrict__ ipw_b, ushort* __restrict__ xpw_b, ushort* __restrict__ opw_b) {
    int t = blockIdx.x * 256 + threadIdx.x;
    if (t < IPW_N) { ipw_b[t] = f2bf(ipw[t]); return; }
    t -= IPW_N;
    if (t < XPW_N) {
        int l = t >> 15, r = (t >> 9) & 63, k = t & 511;
        xpw_b[t] = (r < 48) ? f2bf(xpw[((size_t)l * 48 + r) * DI + k]) : (ushort)0;
        return;
    }
    t -= XPW_N;
    if (t < OPW_N) opw_b[t] = f2bf(opw[t]);
}

// h[m][d] = x[m] * w[d] + b[d]  (fp32 residual stream init)
__global__ void input_proj_kernel(const float* __restrict__ x, const float* __restrict__ w,
                                  const float* __restrict__ b, float* __restrict__ h) {
    int t = blockIdx.x * 256 + threadIdx.x;
    if (t >= MR * DM) return;
    int d = t & (DM - 1);
    int m = t >> 8;
    h[t] = x[m] * w[d] + b[d];
}

// layernorm over 256 cols, bf16 output
__global__ __launch_bounds__(256) void layernorm_bf16_kernel(const float* __restrict__ in,
        const float* __restrict__ w, const float* __restrict__ b, ushort* __restrict__ out) {
    int row = blockIdx.x, t = threadIdx.x;
    float v = in[row * DM + t];
    float s = v, q = v * v;
#pragma unroll
    for (int o = 32; o >= 1; o >>= 1) { s += __shfl_xor(s, o); q += __shfl_xor(q, o); }
    __shared__ float red[8];
    int wid = t >> 6;
    if ((t & 63) == 0) { red[wid] = s; red[4 + wid] = q; }
    __syncthreads();
    s = red[0] + red[1] + red[2] + red[3];
    q = red[4] + red[5] + red[6] + red[7];
    float mu = s * (1.0f / DM);
    float var = q * (1.0f / DM) - mu * mu;
    float rs = rsqrtf(var + 1e-5f);
    out[row * DM + t] = f2bf((v - mu) * rs * w[t] + b[t]);
}

// ---- bf16 MFMA GEMM: C[M,N] = A[M,K] @ W[N,K]^T ----
// MODE 0: bf16 out + bias; MODE 1: f32 out; MODE 2: f32 out += acc + bias
template<int BM, int BN, int WM, int WN, int MODE>
__global__ __launch_bounds__(256) void mfma_gemm_kernel(
        const ushort* __restrict__ A, int lda,
        const ushort* __restrict__ W,
        const float* __restrict__ bias,
        ushort* __restrict__ Cb, float* __restrict__ Cf, int ldc, int K) {
    constexpr int FM = BM / WM / 16;
    constexpr int FN = BN / WN / 16;
    __shared__ __align__(16) char smem[(BM + BN) * 128];
    const int tid = threadIdx.x;
    const int l = tid & 63, w = tid >> 6;
    const int wr = w / WN, wc = w % WN;
    const int bm = blockIdx.x * BM, bn = blockIdx.y * BN;
    const int ldw = K;

    f32x4 acc[FM][FN] = {};

    for (int k0 = 0; k0 < K; k0 += 64) {
#pragma unroll
        for (int i = 0; i < (BM * 128 / 16) / 256; i++) {
            int lin = (i * 256 + tid) * 16;
            int q = lin ^ (((lin >> 7) & 7) << 4);
            g2lds16(A + (size_t)(bm + (q >> 7)) * lda + k0 + ((q & 127) >> 1), smem + lin);
        }
#pragma unroll
        for (int i = 0; i < (BN * 128 / 16) / 256; i++) {
            int lin = (i * 256 + tid) * 16;
            int q = lin ^ (((lin >> 7) & 7) << 4);
            g2lds16(W + (size_t)(bn + (q >> 7)) * ldw + k0 + ((q & 127) >> 1),
                    smem + BM * 128 + lin);
        }
        __syncthreads();
        const int rl = l & 15;
        const int kb0 = ((l >> 4) << 3) * 2;
#pragma unroll
        for (int kk = 0; kk < 2; kk++) {
            short8 af[FM], bfr[FN];
#pragma unroll
            for (int m = 0; m < FM; m++) {
                int off = (wr * (BM / WM) + m * 16 + rl) * 128 + kk * 64 + kb0;
                off ^= ((off >> 7) & 7) << 4;
                af[m] = *(const short8*)(smem + off);
            }
#pragma unroll
            for (int n = 0; n < FN; n++) {
                int off = (wc * (BN / WN) + n * 16 + rl) * 128 + kk * 64 + kb0;
                off ^= ((off >> 7) & 7) << 4;
                bfr[n] = *(const short8*)(smem + BM * 128 + off);
            }
#pragma unroll
            for (int m = 0; m < FM; m++)
#pragma unroll
                for (int n = 0; n < FN; n++)
                    acc[m][n] = __builtin_amdgcn_mfma_f32_16x16x32_bf16(
                        af[m], bfr[n], acc[m][n], 0, 0, 0);
        }
        __syncthreads();
    }

    const int row0 = bm + wr * (BM / WM) + ((l >> 4) << 2);
    const int col0 = bn + wc * (BN / WN) + (l & 15);
#pragma unroll
    for (int m = 0; m < FM; m++) {
#pragma unroll
        for (int n = 0; n < FN; n++) {
            int col = col0 + n * 16;
            float bv = (MODE == 1) ? 0.f : bias[col];
#pragma unroll
            for (int r = 0; r < 4; r++) {
                size_t idx = (size_t)(row0 + m * 16 + r) * ldc + col;
                float v = acc[m][n][r];
                if (MODE == 0) Cb[idx] = f2bf(v + bv);
                else if (MODE == 1) Cf[idx] = v;
                else Cf[idx] += v + bv;
            }
        }
    }
}

// depthwise causal conv (K=4) + SiLU; xz bf16 (ld 1024, cols 0..511) -> u bf16
__global__ __launch_bounds__(256) void conv_silu_kernel(const ushort* __restrict__ xz,
        const float* __restrict__ cw, const float* __restrict__ cb, ushort* __restrict__ u) {
    int t = blockIdx.x * 256 + threadIdx.x;   // MR*DI/8 threads
    int d8 = (t & 63) << 3;
    int m = t >> 6;
    int l = m & (LL - 1);
    const short8 zr = {0, 0, 0, 0, 0, 0, 0, 0};
    const size_t base = (size_t)m * 1024 + d8;
    short8 r3 = *(const short8*)(xz + base);
    short8 r2 = (l >= 1) ? *(const short8*)(xz + base - 1024) : zr;
    short8 r1 = (l >= 2) ? *(const short8*)(xz + base - 2048) : zr;
    short8 r0 = (l >= 3) ? *(const short8*)(xz + base - 3072) : zr;
    short8 o;
#pragma unroll
    for (int j = 0; j < 8; j++) {
        int d = d8 + j;
        float4 w4 = *reinterpret_cast<const float4*>(&cw[d * 4]);
        float a = cb[d] + w4.w * bf2f((ushort)r3[j]);
        a += w4.z * bf2f((ushort)r2[j]);
        a += w4.y * bf2f((ushort)r1[j]);
        a += w4.x * bf2f((ushort)r0[j]);
        o[j] = (short)f2bf(silu_f(a));
    }
    *(short8*)(u + (size_t)m * DI + d8) = o;
}

// delta[m][d] = softplus( x_dbl[m][0..15] . dtw[d][:] + dtb[d] ), x_dbl ld 64
// block = 32 rows x 256 d-cols; dtw register-resident, amortized over 32 rows
__global__ __launch_bounds__(256) void dtproj_kernel(const float* __restrict__ x_dbl,
        const float* __restrict__ dtw, const float* __restrict__ dtb, float* __restrict__ delta) {
    int m0 = (blockIdx.x >> 1) * 32;
    int d = ((blockIdx.x & 1) << 8) + threadIdx.x;
    __shared__ float dts[32][17];
    {
        int i0 = threadIdx.x * 2;
        int r = i0 >> 4, k = i0 & 15;
        float2 v = *reinterpret_cast<const float2*>(&x_dbl[(size_t)(m0 + r) * 64 + k]);
        dts[r][k] = v.x; dts[r][k + 1] = v.y;
    }
    __syncthreads();
    float wreg[16];
#pragma unroll
    for (int q = 0; q < 4; q++) {
        float4 w4 = *reinterpret_cast<const float4*>(&dtw[d * DR + q * 4]);
        wreg[q*4] = w4.x; wreg[q*4+1] = w4.y; wreg[q*4+2] = w4.z; wreg[q*4+3] = w4.w;
    }
    float bv = dtb[d];
    for (int r = 0; r < 32; r++) {
        float acc = bv;
#pragma unroll
        for (int k = 0; k < DR; k++) acc += wreg[k] * dts[r][k];
        float sp = (acc > 20.0f) ? acc : __logf(1.0f + __expf(acc));
        delta[(size_t)(m0 + r) * DI + d] = sp;
    }
}

// ---- chunked parallel scan; u bf16, x_dbl f32 ld 64 ----
// Phase 1: per (b,c,d) thread: chunk state S (from h=0) and sdv = sum(delta).
__global__ __launch_bounds__(256, 4) void scan_phase1_kernel(
        const ushort* __restrict__ u, const float* __restrict__ delta,
        const float* __restrict__ x_dbl, const float* __restrict__ A_log,
        float* __restrict__ sdv, float* __restrict__ Sbuf) {
    int gid = blockIdx.x * 256 + threadIdx.x;
    int d = gid & (DI - 1);
    int c = (gid >> 9) & (NCHUNK - 1);
    int b = gid >> 15;
    float Aval[DS], h[DS];
#pragma unroll
    for (int q = 0; q < 4; q++) {
        float4 a4 = *reinterpret_cast<const float4*>(&A_log[d * DS + q * 4]);
        Aval[q*4+0] = -__expf(a4.x); Aval[q*4+1] = -__expf(a4.y);
        Aval[q*4+2] = -__expf(a4.z); Aval[q*4+3] = -__expf(a4.w);
    }
#pragma unroll
    for (int n = 0; n < DS; n++) h[n] = 0.f;
    int m0 = b * LL + c * CLEN;
    const float* dp = delta + (size_t)m0 * DI + d;
    const ushort* up = u + (size_t)m0 * DI + d;
    const float* xb = x_dbl + (size_t)m0 * 64 + 16;
    float sd = 0.f;
    float dv = dp[0];
    float uv = bf2f(up[0]);
    float Bv[DS];
#pragma unroll
    for (int q = 0; q < 4; q++) {
        float4 b4 = *reinterpret_cast<const float4*>(xb + q * 4);
        Bv[q*4] = b4.x; Bv[q*4+1] = b4.y; Bv[q*4+2] = b4.z; Bv[q*4+3] = b4.w;
    }
    for (int t = 0; t < CLEN; t++) {
        float dvn = 0.f, uvn = 0.f, Bn[DS];
#pragma unroll
        for (int n = 0; n < DS; n++) Bn[n] = 0.f;
        if (t + 1 < CLEN) {
            dvn = dp[(size_t)(t + 1) * DI];
            uvn = bf2f(up[(size_t)(t + 1) * DI]);
            const float* xbn = xb + (size_t)(t + 1) * 64;
#pragma unroll
            for (int q = 0; q < 4; q++) {
                float4 b4 = *reinterpret_cast<const float4*>(xbn + q * 4);
                Bn[q*4] = b4.x; Bn[q*4+1] = b4.y; Bn[q*4+2] = b4.z; Bn[q*4+3] = b4.w;
            }
        }
        sd += dv;
        float du = dv * uv;
#pragma unroll
        for (int n = 0; n < DS; n++) {
            float dA = __expf(dv * Aval[n]);
            h[n] = dA * h[n] + du * Bv[n];
        }
        dv = dvn; uv = uvn;
#pragma unroll
        for (int n = 0; n < DS; n++) Bv[n] = Bn[n];
    }
    size_t base = ((size_t)((b * NCHUNK + c) * DI + d)) * DS;
#pragma unroll
    for (int q = 0; q < 4; q++)
        *reinterpret_cast<float4*>(&Sbuf[base + q * 4]) =
            make_float4(h[q*4], h[q*4+1], h[q*4+2], h[q*4+3]);
    sdv[(b * NCHUNK + c) * DI + d] = sd;
}

// Phase 2: per (b,d,n) thread; P_c = exp(A*sdv_c); Sbuf[c] overwritten with hinit.
__global__ __launch_bounds__(256) void scan_phase2_kernel(
        const float* __restrict__ sdv, const float* __restrict__ A_log,
        float* __restrict__ Sbuf) {
    int gid = blockIdx.x * 256 + threadIdx.x;
    int dn = gid & (DI * DS - 1);
    int b = gid >> 13;
    int n = dn & 15, d = dn >> 4;
    float Aval = -__expf(A_log[d * DS + n]);
    size_t idx0 = (size_t)b * NCHUNK * DI * DS + dn;
    const size_t stride = (size_t)DI * DS;
    int sb0 = b * NCHUNK * DI + d;
    float h = 0.f;
    float Sc = Sbuf[idx0];
    float sd = sdv[sb0];
    for (int c = 0; c < NCHUNK; c++) {
        size_t idx = idx0 + (size_t)c * stride;
        float Sn = 0.f, sdn = 0.f;
        if (c + 1 < NCHUNK) {
            Sn = Sbuf[idx + stride];
            sdn = sdv[sb0 + (c + 1) * DI];
        }
        float Pc = __expf(Aval * sd);
        Sbuf[idx] = h;
        h = Pc * h + Sc;
        Sc = Sn; sd = sdn;
    }
}

// Phase 3 + fused gate: replay chunk from hinit, y = scan_y * silu(res), bf16 out
__global__ __launch_bounds__(256, 4) void scan_phase3_kernel(
        const ushort* __restrict__ u, const float* __restrict__ delta,
        const float* __restrict__ x_dbl, const float* __restrict__ A_log,
        const float* __restrict__ Dp, const float* __restrict__ Sbuf,
        const ushort* __restrict__ xz, ushort* __restrict__ y) {
    int gid = blockIdx.x * 256 + threadIdx.x;
    int d = gid & (DI - 1);
    int c = (gid >> 9) & (NCHUNK - 1);
    int b = gid >> 15;
    float Aval[DS], h[DS];
#pragma unroll
    for (int q = 0; q < 4; q++) {
        float4 a4 = *reinterpret_cast<const float4*>(&A_log[d * DS + q * 4]);
        Aval[q*4+0] = -__expf(a4.x); Aval[q*4+1] = -__expf(a4.y);
        Aval[q*4+2] = -__expf(a4.z); Aval[q*4+3] = -__expf(a4.w);
    }
    size_t base = ((size_t)((b * NCHUNK + c) * DI + d)) * DS;
#pragma unroll
    for (int q = 0; q < 4; q++) {
        float4 h4 = *reinterpret_cast<const float4*>(&Sbuf[base + q * 4]);
        h[q*4] = h4.x; h[q*4+1] = h4.y; h[q*4+2] = h4.z; h[q*4+3] = h4.w;
    }
    float Dval = Dp[d];
    int m0 = b * LL + c * CLEN;
    const float* dp = delta + (size_t)m0 * DI + d;
    const ushort* up = u + (size_t)m0 * DI + d;
    const float* xb = x_dbl + (size_t)m0 * 64 + 16;
    const ushort* rp = xz + (size_t)m0 * 1024 + 512 + d;
    ushort* yp = y + (size_t)m0 * DI + d;
    float dv = dp[0];
    float uv = bf2f(up[0]);
    float rv = bf2f(rp[0]);
    float Bv[DS], Cv[DS];
#pragma unroll
    for (int q = 0; q < 4; q++) {
        float4 b4 = *reinterpret_cast<const float4*>(xb + q * 4);
        float4 c4 = *reinterpret_cast<const float4*>(xb + 16 + q * 4);
        Bv[q*4] = b4.x; Bv[q*4+1] = b4.y; Bv[q*4+2] = b4.z; Bv[q*4+3] = b4.w;
        Cv[q*4] = c4.x; Cv[q*4+1] = c4.y; Cv[q*4+2] = c4.z; Cv[q*4+3] = c4.w;
    }
    for (int t = 0; t < CLEN; t++) {
        float dvn = 0.f, uvn = 0.f, rvn = 0.f, Bn[DS], Cn[DS];
#pragma unroll
        for (int n = 0; n < DS; n++) { Bn[n] = 0.f; Cn[n] = 0.f; }
        if (t + 1 < CLEN) {
            dvn = dp[(size_t)(t + 1) * DI];
            uvn = bf2f(up[(size_t)(t + 1) * DI]);
            rvn = bf2f(rp[(size_t)(t + 1) * 1024]);
            const float* xbn = xb + (size_t)(t + 1) * 64;
#pragma unroll
            for (int q = 0; q < 4; q++) {
                float4 b4 = *reinterpret_cast<const float4*>(xbn + q * 4);
                float4 c4 = *reinterpret_cast<const float4*>(xbn + 16 + q * 4);
                Bn[q*4] = b4.x; Bn[q*4+1] = b4.y; Bn[q*4+2] = b4.z; Bn[q*4+3] = b4.w;
                Cn[q*4] = c4.x; Cn[q*4+1] = c4.y; Cn[q*4+2] = c4.z; Cn[q*4+3] = c4.w;
            }
        }
        float du = dv * uv;
        float acc = Dval * uv;
#pragma unroll
        for (int n = 0; n < DS; n++) {
            float dA = __expf(dv * Aval[n]);
            h[n] = dA * h[n] + du * Bv[n];
            acc += h[n] * Cv[n];
        }
        yp[(size_t)t * DI] = f2bf(acc * silu_f(rv));
        dv = dvn; uv = uvn; rv = rvn;
#pragma unroll
        for (int n = 0; n < DS; n++) { Bv[n] = Bn[n]; Cv[n] = Cn[n]; }
    }
}

// pool stage 1: partial[(b*8+slice)][dm] = sum over 128 l's
__global__ __launch_bounds__(256) void pool_partial_kernel(const ushort* __restrict__ ln,
                                                           float* __restrict__ partial) {
    int bs = blockIdx.x;            // 0..63
    int b = bs >> 3, sl = bs & 7;
    int t = threadIdx.x;            // dm
    int l0 = sl * 128;
    float s = 0.f;
    for (int l = 0; l < 128; l++) s += bf2f(ln[(size_t)(b * LL + l0 + l) * DM + t]);
    partial[(bs << 8) + t] = s;
}

__global__ void cls_kernel(const float* __restrict__ partial, const float* __restrict__ cw,
                           const float* __restrict__ cb, float* __restrict__ out) {
    int t = threadIdx.x;
    if (t >= NB * NC) return;
    int b = t / NC, c = t % NC;
    float s = 0.f;
    for (int k = 0; k < DM; k++) {
        float p = 0.f;
#pragma unroll
        for (int sl = 0; sl < 8; sl++) p += partial[((b * 8 + sl) << 8) + k];
        s += p * cw[c * DM + k];
    }
    out[t] = cb[c] + s * (1.0f / LL);
}

extern "C" void kernel_launch(void* const* d_in, const int* in_sizes, int n_in,
                              void* d_out, int out_size, void* d_ws, size_t ws_size,
                              hipStream_t stream) {
    const float* x       = (const float*)d_in[0];
    const float* input_w = (const float*)d_in[1];
    const float* input_b = (const float*)d_in[2];
    const float* ln_w    = (const float*)d_in[3];
    const float* ln_b    = (const float*)d_in[4];
    const float* ipw     = (const float*)d_in[5];
    const float* ipb     = (const float*)d_in[6];
    const float* cw      = (const float*)d_in[7];
    const float* cb      = (const float*)d_in[8];
    const float* xpw     = (const float*)d_in[9];
    const float* dtw     = (const float*)d_in[10];
    const float* dtb     = (const float*)d_in[11];
    const float* A_log   = (const float*)d_in[12];
    const float* Dp      = (const float*)d_in[13];
    const float* opw     = (const float*)d_in[14];
    const float* opb     = (const float*)d_in[15];
    const float* norm_w  = (const float*)d_in[16];
    const float* norm_b  = (const float*)d_in[17];
    const float* cls_w   = (const float*)d_in[18];
    const float* cls_b   = (const float*)d_in[19];
    float* out = (float*)d_out;
    float* ws = (float*)d_ws;

    float*  hres   = ws;                                   // MR*DM f32
    ushort* xz     = (ushort*)(hres + (size_t)MR * DM);    // MR*1024 bf16
    ushort* ub     = xz + (size_t)MR * 1024;               // MR*DI bf16
    float*  delta  = (float*)(ub + (size_t)MR * DI);       // MR*DI f32
    float*  x_dbl  = delta + (size_t)MR * DI;              // MR*64 f32
    float*  sdvb   = x_dbl + (size_t)MR * 64;              // NB*NCHUNK*DI f32
    float*  Sbuf   = sdvb + (size_t)NB * NCHUNK * DI;      // NB*NCHUNK*DI*DS f32
    float*  partial= Sbuf + (size_t)NB * NCHUNK * DI * DS; // 64*256 f32
    ushort* ygate  = (ushort*)(partial + 64 * 256);        // MR*DI bf16
    ushort* hln    = ygate + (size_t)MR * DI;              // MR*DM bf16
    ushort* ipw_b  = hln + (size_t)MR * DM;                // IPW_N
    ushort* xpw_b  = ipw_b + IPW_N;                        // XPW_N
    ushort* opw_b  = xpw_b + XPW_N;                        // OPW_N

    convert_weights_kernel<<<(IPW_N + XPW_N + OPW_N) / 256, 256, 0, stream>>>(
        ipw, xpw, opw, ipw_b, xpw_b, opw_b);
    input_proj_kernel<<<MR * DM / 256, 256, 0, stream>>>(x, input_w, input_b, hres);

    for (int i = 0; i < NL; i++) {
        layernorm_bf16_kernel<<<MR, 256, 0, stream>>>(hres, ln_w + i * DM, ln_b + i * DM, hln);
        mfma_gemm_kernel<128, 128, 2, 2, 0><<<dim3(MR / 128, 1024 / 128), 256, 0, stream>>>(
            hln, DM, ipw_b + (size_t)i * 2 * DI * DM, ipb + (size_t)i * 2 * DI,
            xz, nullptr, 1024, DM);
        conv_silu_kernel<<<MR * DI / 8 / 256, 256, 0, stream>>>(xz, cw + i * DI * DC, cb + i * DI, ub);
        mfma_gemm_kernel<64, 64, 4, 1, 1><<<dim3(MR / 64, 1), 256, 0, stream>>>(
            ub, DI, xpw_b + (size_t)i * 64 * DI, nullptr, nullptr, x_dbl, 64, DI);
        dtproj_kernel<<<(MR / 32) * 2, 256, 0, stream>>>(
            x_dbl, dtw + i * DI * DR, dtb + i * DI, delta);
        scan_phase1_kernel<<<NB * NCHUNK * DI / 256, 256, 0, stream>>>(
            ub, delta, x_dbl, A_log + i * DI * DS, sdvb, Sbuf);
        scan_phase2_kernel<<<NB * DI * DS / 256, 256, 0, stream>>>(
            sdvb, A_log + i * DI * DS, Sbuf);
        scan_phase3_kernel<<<NB * NCHUNK * DI / 256, 256, 0, stream>>>(
            ub, delta, x_dbl, A_log + i * DI * DS, Dp + i * DI, Sbuf, xz, ygate);
        mfma_gemm_kernel<64, 128, 2, 2, 2><<<dim3(MR / 64, DM / 128), 256, 0, stream>>>(
            ygate, DI, opw_b + (size_t)i * DM * DI, opb + (size_t)i * DM,
            nullptr, hres, DM, DI);
    }

    layernorm_bf16_kernel<<<MR, 256, 0, stream>>>(hres, norm_w, norm_b, hln);
    pool_partial_kernel<<<64, 256, 0, stream>>>(hln, partial);
    cls_kernel<<<1, 128, 0, stream>>>(partial, cls_w, cls_b, out);
}